// Round 10
// baseline (235.769 us; speedup 1.0000x reference)
//
#include <hip/hip_runtime.h>
#include <hip/hip_bf16.h>

// Problem constants (match reference)
#define NN 50000
#define NE 800000
#define HID 128
#define NG 512
#define BN_EPS 1e-5f

typedef __attribute__((ext_vector_type(8))) short bf16x8;
typedef __attribute__((ext_vector_type(4))) float f32x4;

__device__ __forceinline__ ushort f2bf(float f) {
    uint u = __float_as_uint(f);
    uint r = (u + 0x7fffu + ((u >> 16) & 1u)) >> 16;
    return (ushort)r;
}
__device__ __forceinline__ float bf_lo(uint v) { return __uint_as_float(v << 16); }
__device__ __forceinline__ float bf_hi(uint v) { return __uint_as_float(v & 0xffff0000u); }

__device__ __forceinline__ void acc4(float* a, uint4 v0, uint4 v1, uint4 v2, uint4 v3) {
    a[0] += (bf_lo(v0.x) + bf_lo(v1.x)) + (bf_lo(v2.x) + bf_lo(v3.x));
    a[1] += (bf_hi(v0.x) + bf_hi(v1.x)) + (bf_hi(v2.x) + bf_hi(v3.x));
    a[2] += (bf_lo(v0.y) + bf_lo(v1.y)) + (bf_lo(v2.y) + bf_lo(v3.y));
    a[3] += (bf_hi(v0.y) + bf_hi(v1.y)) + (bf_hi(v2.y) + bf_hi(v3.y));
    a[4] += (bf_lo(v0.z) + bf_lo(v1.z)) + (bf_lo(v2.z) + bf_lo(v3.z));
    a[5] += (bf_hi(v0.z) + bf_hi(v1.z)) + (bf_hi(v2.z) + bf_hi(v3.z));
    a[6] += (bf_lo(v0.w) + bf_lo(v1.w)) + (bf_lo(v2.w) + bf_lo(v3.w));
    a[7] += (bf_hi(v0.w) + bf_hi(v1.w)) + (bf_hi(v2.w) + bf_hi(v3.w));
}

// one "quarter" = 16 neighbors = 4 predicated row gathers per lane-group
__device__ __forceinline__ void load_q(const uint4* fb, int sl, int q, int sub, int cl,
                                       int d, int dm1, uint4* v) {
#pragma unroll
    for (int t = 0; t < 4; ++t) {
        int k = q * 16 + t * 4 + sub;
        int idx = __shfl(sl, min(k, dm1));
        uint4 vv = make_uint4(0u, 0u, 0u, 0u);
        if (k < d) vv = fb[(size_t)idx * 16 + cl];
        v[t] = vv;
    }
}

// ---------------------------------------------------------------------------
// CSR build v3: LDS histogram, latency-pipelined (proven through R18).
// R22: aggregate dependency chain flattened. Per node the old path was
// {sl load -> main-round loads -> VALU -> tail loads -> VALU} (~2 exposed
// latencies + head). Now: all 4 nodes' index chunks prefetched at wave
// entry; quarters (16 neighbors each, k<d predicated, clamped shfl sel)
// issue 2-deep before consumption; d>64 falls to the R21 chunk loop.
// ---------------------------------------------------------------------------
#define NCH 64            // edge chunks
#define CHE 12500         // edges per chunk (NE/NCH)
#define NRNG 4            // node ranges
#define HRNG 12500        // nodes per range
#define HWORDS 6250       // packed uint words per range (25KB LDS)
#define HIST_BLOCKS (NCH * NRNG)  // 256
#define CONV_BLOCKS 6250  // NN*HID/4 float4 / 256 exact
#define WPREP_BLOCKS 32   // 128 wave-units / 4
#define POOLZ_BLOCKS 64   // NG*HID/4 float4 / 256 exact
#define PH_GRID (HIST_BLOCKS + CONV_BLOCKS + WPREP_BLOCKS + POOLZ_BLOCKS)

__global__ __launch_bounds__(256) void prep_hist_kernel(const int* __restrict__ ei,
                                                        ushort* __restrict__ rank,
                                                        ushort* __restrict__ blockcnt,
                                                        const float* __restrict__ x,
                                                        ushort* __restrict__ xb,
                                                        const float* __restrict__ W0,
                                                        const float* __restrict__ W1,
                                                        const float* __restrict__ W2,
                                                        const float* __restrict__ W3,
                                                        ushort* __restrict__ Wp,
                                                        float* __restrict__ pooled) {
    __shared__ uint hh[HWORDS];  // 25KB -> 6 blocks/CU
    uint b = blockIdx.x;
    if (b < HIST_BLOCKS) {
        int c = b >> 2;   // edge chunk
        int r = b & 3;    // node range
        for (int i = threadIdx.x; i < HWORDS; i += 256) hh[i] = 0;
        __syncthreads();
        int base = c * CHE;
        int lo = r * HRNG;
        const int4* ev = (const int4*)(ei + NE + base);  // CHE%4==0, 16B aligned
        const int nvec = CHE / 4;                        // 3125
        int k4 = threadIdx.x;
        int4 cur;
        bool have = k4 < nvec;
        if (have) cur = ev[k4];
        while (have) {
            int kn = k4 + 256;
            bool hn = kn < nvec;
            int4 nxt;
            if (hn) nxt = ev[kn];  // prefetch next vector while atomics issue
            int e0 = base + k4 * 4;
#pragma unroll
            for (int j = 0; j < 4; ++j) {
                int d = (j == 0) ? cur.x : (j == 1) ? cur.y : (j == 2) ? cur.z : cur.w;
                int local = d - lo;
                if ((unsigned)local < (unsigned)HRNG) {
                    uint sh = (local & 1) << 4;
                    uint old = atomicAdd(&hh[local >> 1], 1u << sh);
                    rank[e0 + j] = (ushort)((old >> sh) & 0xffffu);
                }
            }
            k4 = kn;
            cur = nxt;
            have = hn;
        }
        __syncthreads();
        // coalesced writeback of this (chunk, range)'s counts
        uint* dstw = (uint*)(blockcnt + (size_t)c * NN) + r * HWORDS;
        for (int i = threadIdx.x; i < HWORDS; i += 256) dstw[i] = hh[i];
    } else if (b < HIST_BLOCKS + CONV_BLOCKS) {
        int i = (b - HIST_BLOCKS) * 256 + threadIdx.x;  // < 1,600,000 exactly
        float4 v = ((const float4*)x)[i];
        ushort4 o;
        o.x = f2bf(v.x);
        o.y = f2bf(v.y);
        o.z = f2bf(v.z);
        o.w = f2bf(v.w);
        ((ushort4*)xb)[i] = o;
    } else if (b < HIST_BLOCKS + CONV_BLOCKS + WPREP_BLOCKS) {
        int wu = (b - HIST_BLOCKS - CONV_BLOCKS) * 4 + (threadIdx.x >> 6);
        if (wu >= 128) return;
        int lane = threadIdx.x & 63;
        int m = wu >> 5;
        int g = wu & 31;
        int tile = g >> 2;
        int chunk = g & 3;
        const float* W = (m == 0) ? W0 : (m == 1) ? W1 : (m == 2) ? W2 : W3;
        int col = tile * 16 + (lane & 15);
        int k0 = chunk * 32 + (lane >> 4) * 8;
        ushort* dst = Wp + ((size_t)wu * 64 + lane) * 8;
#pragma unroll
        for (int j = 0; j < 8; ++j) dst[j] = f2bf(W[col * HID + k0 + j]);
    } else {
        int i = (b - HIST_BLOCKS - CONV_BLOCKS - WPREP_BLOCKS) * 256 + threadIdx.x;  // < 16384
        ((float4*)pooled)[i] = make_float4(0.f, 0.f, 0.f, 0.f);
    }
}

// ---------------------------------------------------------------------------
// Fused chunk-column scan + block-level deg scan (kept from R16).
// ---------------------------------------------------------------------------
__global__ __launch_bounds__(256) void scan1_kernel(ushort* __restrict__ blockcnt,
                                                    int* __restrict__ deg,
                                                    int* __restrict__ row_start,
                                                    int* __restrict__ bsums, int n) {
    __shared__ int wsum[4];
    __shared__ int degsh[256];
    int i = blockIdx.x * 256 + threadIdx.x;
    int w = blockIdx.x * 128 + (int)threadIdx.x;  // packed word = 2 nodes
    if (threadIdx.x < 128 && w < NN / 2) {
        uint run_lo = 0, run_hi = 0;
        uint* col = (uint*)blockcnt + w;
#pragma unroll 4
        for (int c = 0; c < NCH; ++c) {
            uint x = col[(size_t)c * (NN / 2)];
            col[(size_t)c * (NN / 2)] = run_lo | (run_hi << 16);
            run_lo += x & 0xffffu;
            run_hi += x >> 16;
        }
        degsh[2 * (int)threadIdx.x] = (int)run_lo;
        degsh[2 * (int)threadIdx.x + 1] = (int)run_hi;
        ((int2*)deg)[w] = make_int2((int)run_lo, (int)run_hi);
    }
    __syncthreads();
    int lane = threadIdx.x & 63;
    int wid = threadIdx.x >> 6;
    int v = (i < n) ? degsh[threadIdx.x] : 0;
    int sc = v;
#pragma unroll
    for (int off = 1; off < 64; off <<= 1) {
        int t = __shfl_up(sc, off);
        if (lane >= off) sc += t;
    }
    if (lane == 63) wsum[wid] = sc;
    __syncthreads();
    int wpre = 0;
#pragma unroll
    for (int k = 0; k < 4; ++k) wpre += (k < wid) ? wsum[k] : 0;
    if (i < n) row_start[i] = wpre + sc - v;  // block-exclusive
    if (threadIdx.x == 255) bsums[blockIdx.x] = wpre + sc;
}

// merged scan2+scan3: each block reduces bsums[0..blockIdx) and adds.
__global__ __launch_bounds__(256) void scan23_kernel(int* __restrict__ row_start,
                                                     const int* __restrict__ bsums, int n) {
    __shared__ int sred[4];
    int v = (threadIdx.x < blockIdx.x) ? bsums[threadIdx.x] : 0;
#pragma unroll
    for (int off = 32; off > 0; off >>= 1) v += __shfl_xor(v, off);
    if ((threadIdx.x & 63) == 0) sred[threadIdx.x >> 6] = v;
    __syncthreads();
    int total = sred[0] + sred[1] + sred[2] + sred[3];
    int i = blockIdx.x * 256 + threadIdx.x;
    if (i < n) row_start[i] += total;
}

// atomic-free fill, 4 edges/thread.
__global__ __launch_bounds__(256) void fill_kernel(const int* __restrict__ ei,
                                                   const int* __restrict__ row_start,
                                                   const ushort* __restrict__ rank,
                                                   const ushort* __restrict__ blockcnt,
                                                   ushort* __restrict__ srclist) {
    int e4 = blockIdx.x * 256 + threadIdx.x;
    if (e4 >= NE / 4) return;
    int4 src = ((const int4*)ei)[e4];
    int4 dst = ((const int4*)(ei + NE))[e4];
    ushort4 rk = ((const ushort4*)rank)[e4];
    int c = e4 / (CHE / 4);  // chunk id
    const ushort* off = blockcnt + (size_t)c * NN;
    int p0 = row_start[dst.x] + off[dst.x] + rk.x;
    int p1 = row_start[dst.y] + off[dst.y] + rk.y;
    int p2 = row_start[dst.z] + off[dst.z] + rk.z;
    int p3 = row_start[dst.w] + off[dst.w] + rk.w;
    srclist[p0] = (ushort)src.x;
    srclist[p1] = (ushort)src.y;
    srclist[p2] = (ushort)src.z;
    srclist[p3] = (ushort)src.w;
}

// ---------------------------------------------------------------------------
// FUSED SAGE layer (R22): R19 shape (4 waves x 4 nodes serial), flattened
// gather pipeline.
//   Wave entry: prefetch row_start/deg/index-chunk for ALL 4 nodes (4
//   coalesced wave-loads).
//   Per node: quarters of 16 neighbors; q0+q1 loads issued back-to-back
//   (8 predicated gathers in flight) before any consumption; q2/q3 issued
//   ahead of the previous quarter's consume (d>32 rare). d>64 -> chunk loop.
//   Phase 2: GEMM col-tiles 2/wave, A-mean from LDS, A-root from feat.
// ---------------------------------------------------------------------------
template <bool POOL>
__global__ __launch_bounds__(256) void sage_fused(const ushort* __restrict__ feat,
                                                  const int* __restrict__ row_start,
                                                  const int* __restrict__ deg,
                                                  const ushort* __restrict__ srclist,
                                                  const ushort* __restrict__ WpL,
                                                  const float* __restrict__ bias,
                                                  const int* __restrict__ batch,
                                                  void* __restrict__ outv) {
    __shared__ ushort As[16][136];  // 4.25KB, padded rows
    int lane = threadIdx.x & 63;
    int wv = threadIdx.x >> 6;
    int base = blockIdx.x * 16;  // 3125 blocks * 16 = 50000 exact
    int cl = lane & 15;
    int sub = lane >> 4;
    const uint4* fb = (const uint4*)feat;  // row stride = 16 uint4 (256B)

    // ---- wave-entry prefetch: meta + first index chunk for all 4 nodes ----
    int nodes0 = base + wv * 4;
    int s0a[4], dda[4], sla[4];
#pragma unroll
    for (int i = 0; i < 4; ++i) {
        s0a[i] = row_start[nodes0 + i];
        dda[i] = deg[nodes0 + i];
    }
#pragma unroll
    for (int i = 0; i < 4; ++i) {
        int cm = max(dda[i] - 1, 0);
        sla[i] = (int)srclist[s0a[i] + min(lane, cm)];
    }

    // ---- Phase 1: aggregate 4 nodes on this wave ----
#pragma unroll 1
    for (int i = 0; i < 4; ++i) {
        int d = dda[i];
        int dm1 = d - 1;
        int sl = sla[i];

        float a[8];
#pragma unroll
        for (int k = 0; k < 8; ++k) a[k] = 0.f;

        uint4 v01[8];
        load_q(fb, sl, 0, sub, cl, d, dm1, v01);
        load_q(fb, sl, 1, sub, cl, d, dm1, v01 + 4);
        acc4(a, v01[0], v01[1], v01[2], v01[3]);
        if (d > 16) {
            uint4 v2[4];
            if (d > 32) load_q(fb, sl, 2, sub, cl, d, dm1, v2);
            acc4(a, v01[4], v01[5], v01[6], v01[7]);
            if (d > 32) {
                uint4 v3[4];
                if (d > 48) load_q(fb, sl, 3, sub, cl, d, dm1, v3);
                acc4(a, v2[0], v2[1], v2[2], v2[3]);
                if (d > 48) acc4(a, v3[0], v3[1], v3[2], v3[3]);
            }
        }
        if (d > 64) {  // rare correctness path: remaining chunks, R21 structure
            int s0 = s0a[i];
#pragma unroll 1
            for (int jb = 64; jb < d; jb += 64) {
                int sl2 = (int)srclist[s0 + min(jb + lane, dm1)];
                int lim = min(jb + 64, d);
                int j = jb;
                for (; j + 16 <= lim; j += 16) {
                    int b0 = j - jb;
                    int i0 = __shfl(sl2, b0 + sub);
                    int i1 = __shfl(sl2, b0 + 4 + sub);
                    int i2 = __shfl(sl2, b0 + 8 + sub);
                    int i3 = __shfl(sl2, b0 + 12 + sub);
                    uint4 w0 = fb[(size_t)i0 * 16 + cl];
                    uint4 w1 = fb[(size_t)i1 * 16 + cl];
                    uint4 w2 = fb[(size_t)i2 * 16 + cl];
                    uint4 w3 = fb[(size_t)i3 * 16 + cl];
                    acc4(a, w0, w1, w2, w3);
                }
                if (j < lim) {
                    int k0 = j + sub;
                    int k1 = j + 4 + sub;
                    int k2 = j + 8 + sub;
                    int k3 = j + 12 + sub;
                    int i0 = __shfl(sl2, min(k0, dm1) - jb);
                    int i1 = __shfl(sl2, min(k1, dm1) - jb);
                    int i2 = __shfl(sl2, min(k2, dm1) - jb);
                    int i3 = __shfl(sl2, min(k3, dm1) - jb);
                    uint4 w0 = make_uint4(0u, 0u, 0u, 0u);
                    uint4 w1 = make_uint4(0u, 0u, 0u, 0u);
                    uint4 w2 = make_uint4(0u, 0u, 0u, 0u);
                    uint4 w3 = make_uint4(0u, 0u, 0u, 0u);
                    if (k0 < d) w0 = fb[(size_t)i0 * 16 + cl];
                    if (k1 < d) w1 = fb[(size_t)i1 * 16 + cl];
                    if (k2 < d) w2 = fb[(size_t)i2 * 16 + cl];
                    if (k3 < d) w3 = fb[(size_t)i3 * 16 + cl];
                    acc4(a, w0, w1, w2, w3);
                }
            }
        }

#pragma unroll
        for (int k = 0; k < 8; ++k) {
            float v = a[k];
            v += __shfl_xor(v, 16);
            v += __shfl_xor(v, 32);
            a[k] = v;
        }

        if (sub == 0) {
            float inv = 1.0f / fmaxf((float)d, 1.0f);
            uint4 o;
            o.x = (uint)f2bf(a[0] * inv) | ((uint)f2bf(a[1] * inv) << 16);
            o.y = (uint)f2bf(a[2] * inv) | ((uint)f2bf(a[3] * inv) << 16);
            o.z = (uint)f2bf(a[4] * inv) | ((uint)f2bf(a[5] * inv) << 16);
            o.w = (uint)f2bf(a[6] * inv) | ((uint)f2bf(a[7] * inv) << 16);
            *(uint4*)&As[wv * 4 + i][cl * 8] = o;
        }
    }
    __syncthreads();

    // ---- Phase 2: GEMM, col-tiles {wv*2, wv*2+1} ----
    int mrow = lane & 15;
    int quad = lane >> 4;

    f32x4 acc[2];
    acc[0] = (f32x4){0.f, 0.f, 0.f, 0.f};
    acc[1] = (f32x4){0.f, 0.f, 0.f, 0.f};

    const ushort* arow_r = feat + ((size_t)(base + mrow)) * HID + quad * 8;

#pragma unroll
    for (int half = 0; half < 2; ++half) {
        const ushort* wb = WpL + (size_t)half * 16384 + (size_t)lane * 8;
#pragma unroll
        for (int c = 0; c < 4; ++c) {
            bf16x8 a;
            if (half == 0) {
                a = *(const bf16x8*)&As[mrow][c * 32 + quad * 8];
            } else {
                a = *(const bf16x8*)(arow_r + c * 32);
            }
#pragma unroll
            for (int tt = 0; tt < 2; ++tt) {
                int t = wv * 2 + tt;
                bf16x8 b = *(const bf16x8*)(wb + (size_t)(t * 4 + c) * 512);
                acc[tt] = __builtin_amdgcn_mfma_f32_16x16x32_bf16(a, b, acc[tt], 0, 0, 0);
            }
        }
    }

    if (POOL) {
        float* pooled = (float*)outv;
        int rbase = base + quad * 4;
        int g0 = batch[rbase + 0];
        int g1 = batch[rbase + 1];
        int g2 = batch[rbase + 2];
        int g3 = batch[rbase + 3];
#pragma unroll
        for (int tt = 0; tt < 2; ++tt) {
            int col = (wv * 2 + tt) * 16 + mrow;
            float bv = bias[col];
            float v0 = acc[tt][0] + bv;
            float v1 = acc[tt][1] + bv;
            float v2 = acc[tt][2] + bv;
            float v3 = acc[tt][3] + bv;
            int cg = g0;
            float s = v0;
            if (g1 == cg) s += v1; else { atomicAdd(&pooled[(size_t)cg * HID + col], s); cg = g1; s = v1; }
            if (g2 == cg) s += v2; else { atomicAdd(&pooled[(size_t)cg * HID + col], s); cg = g2; s = v2; }
            if (g3 == cg) s += v3; else { atomicAdd(&pooled[(size_t)cg * HID + col], s); cg = g3; s = v3; }
            atomicAdd(&pooled[(size_t)cg * HID + col], s);
        }
    } else {
        ushort* out = (ushort*)outv;
#pragma unroll
        for (int tt = 0; tt < 2; ++tt) {
            int col = (wv * 2 + tt) * 16 + mrow;
            float bv = bias[col];
#pragma unroll
            for (int r = 0; r < 4; ++r) {
                int row = base + quad * 4 + r;
                out[(size_t)row * HID + col] = f2bf(acc[tt][r] + bv);
            }
        }
    }
}

// ---------------------------------------------------------------------------
// Tail: lin1 + BN(eval) + relu + lin2. One block (128 thr) per graph.
// ---------------------------------------------------------------------------
__global__ __launch_bounds__(128) void tail_kernel(const float* __restrict__ pooled,
                                                   const float* __restrict__ lin1_w,
                                                   const float* __restrict__ lin1_b,
                                                   const float* __restrict__ lin2_w,
                                                   const float* __restrict__ lin2_b,
                                                   const float* __restrict__ gamma,
                                                   const float* __restrict__ beta,
                                                   const float* __restrict__ rmean,
                                                   const float* __restrict__ rvar,
                                                   float* __restrict__ out) {
    __shared__ float Wt[64 * 128];  // Wt[k][c ^ (k&31)] = lin1_w[c][k0+k]
    __shared__ float p[128];
    __shared__ float tbuf[128];
    int g = blockIdx.x;
    int c = threadIdx.x;
    p[c] = pooled[g * HID + c];
    float acc = lin1_b[c];
    int kk = c & 63;
    int chalf = c >> 6;
    for (int k0 = 0; k0 < 128; k0 += 64) {
        __syncthreads();
        for (int i = 0; i < 64; ++i) {
            int crow = i * 2 + chalf;
            float v = lin1_w[crow * HID + k0 + kk];
            Wt[kk * 128 + (crow ^ (kk & 31))] = v;
        }
        __syncthreads();
#pragma unroll
        for (int k = 0; k < 64; ++k) {
            acc += p[k0 + k] * Wt[k * 128 + (c ^ (k & 31))];
        }
    }
    float v = (acc - rmean[c]) * rsqrtf(rvar[c] + BN_EPS) * gamma[c] + beta[c];
    v = fmaxf(v, 0.f);
    tbuf[c] = v;
    __syncthreads();
    int j = c >> 6;
    int lane = c & 63;
    float partial = tbuf[lane] * lin2_w[j * HID + lane] +
                    tbuf[lane + 64] * lin2_w[j * HID + lane + 64];
    for (int off = 32; off > 0; off >>= 1) partial += __shfl_down(partial, off);
    if (lane == 0) out[g * 2 + j] = partial + lin2_b[j];
}

// ---------------------------------------------------------------------------
extern "C" void kernel_launch(void* const* d_in, const int* in_sizes, int n_in,
                              void* d_out, int out_size, void* d_ws, size_t ws_size,
                              hipStream_t stream) {
    const float* x = (const float*)d_in[0];
    const int* ei = (const int*)d_in[1];      // [2][E]
    const int* batch = (const int*)d_in[2];   // [N]
    const float* W1l = (const float*)d_in[3];
    const float* b1 = (const float*)d_in[4];
    const float* W1r = (const float*)d_in[5];
    const float* W2l = (const float*)d_in[6];
    const float* b2 = (const float*)d_in[7];
    const float* W2r = (const float*)d_in[8];
    const float* lin1_w = (const float*)d_in[9];
    const float* lin1_b = (const float*)d_in[10];
    const float* lin2_w = (const float*)d_in[11];
    const float* lin2_b = (const float*)d_in[12];
    const float* gamma = (const float*)d_in[13];
    const float* beta = (const float*)d_in[14];
    const float* rmean = (const float*)d_in[15];
    const float* rvar = (const float*)d_in[16];
    float* out = (float*)d_out;

    const int N = NN, E = NE;

    // workspace carve (256B aligned)
    char* p = (char*)d_ws;
    auto carve = [&](size_t bytes) {
        void* r = (void*)p;
        p += (bytes + 255) & ~(size_t)255;
        return r;
    };
    int* deg = (int*)carve((size_t)N * 4);
    int* row_start = (int*)carve((size_t)N * 4);
    int* bsums = (int*)carve(1024 * 4);
    ushort* rank = (ushort*)carve((size_t)E * 2);
    ushort* blockcnt = (ushort*)carve((size_t)NCH * NN * 2);  // 6.4 MB
    ushort* srclist = (ushort*)carve((size_t)E * 2 + 64);
    ushort* xb = (ushort*)carve((size_t)N * HID * 2);
    ushort* h1 = (ushort*)carve((size_t)N * HID * 2);
    float* pooled = (float*)carve((size_t)NG * HID * 4);
    ushort* Wp = (ushort*)carve(4 * 32 * 64 * 8 * 2);  // 128 KB

    // merged front-end: LDS hist + convert + weight pack + pooled zero.
    prep_hist_kernel<<<PH_GRID, 256, 0, stream>>>(ei, rank, blockcnt, x, xb,
                                                  W1l, W1r, W2l, W2r, Wp, pooled);

    // fused chunk-column scan + block deg scan, then cross-block fixup
    const int scanBlocks = (N + 255) / 256;  // 196
    scan1_kernel<<<scanBlocks, 256, 0, stream>>>(blockcnt, deg, row_start, bsums, N);
    scan23_kernel<<<scanBlocks, 256, 0, stream>>>(row_start, bsums, N);
    fill_kernel<<<(E / 4 + 255) / 256, 256, 0, stream>>>(ei, row_start, rank, blockcnt, srclist);

    // fused layers: 3125 blocks x 4 waves x 4 nodes (R19 shape)
    sage_fused<false><<<N / 16, 256, 0, stream>>>(xb, row_start, deg, srclist, Wp, b1,
                                                  nullptr, h1);
    sage_fused<true><<<N / 16, 256, 0, stream>>>(h1, row_start, deg, srclist, Wp + 32768, b2,
                                                 batch, pooled);
    // tail
    tail_kernel<<<NG, 128, 0, stream>>>(pooled, lin1_w, lin1_b, lin2_w, lin2_b,
                                        gamma, beta, rmean, rvar, out);
}

// Round 12
// 227.139 us; speedup vs baseline: 1.0380x; 1.0380x over previous
//
#include <hip/hip_runtime.h>
#include <hip/hip_bf16.h>

// Problem constants (match reference)
#define NN 50000
#define NE 800000
#define HID 128
#define NG 512
#define BN_EPS 1e-5f

typedef __attribute__((ext_vector_type(8))) short bf16x8;
typedef __attribute__((ext_vector_type(4))) float f32x4;

__device__ __forceinline__ ushort f2bf(float f) {
    uint u = __float_as_uint(f);
    uint r = (u + 0x7fffu + ((u >> 16) & 1u)) >> 16;
    return (ushort)r;
}
__device__ __forceinline__ float bf_lo(uint v) { return __uint_as_float(v << 16); }
__device__ __forceinline__ float bf_hi(uint v) { return __uint_as_float(v & 0xffff0000u); }

// ---------------------------------------------------------------------------
// CSR build v3: LDS histogram, latency-pipelined (proven through R18).
// R24 = resubmit of R23 (GPU acquisition timed out; kernel never measured).
// R23 = R21 (best, 234.3us) + R22's SCALAR prefetch only. R22's uint4
// 2-deep buffering cost 28 VGPR (40->68) -> occupancy 46->26% -> regression;
// here we hoist only row_start/deg/index-chunk (scalar, ~12 VGPR) to kill
// the per-node sl-load head, keeping R21's gather body verbatim.
// ---------------------------------------------------------------------------
#define NCH 64            // edge chunks
#define CHE 12500         // edges per chunk (NE/NCH)
#define NRNG 4            // node ranges
#define HRNG 12500        // nodes per range
#define HWORDS 6250       // packed uint words per range (25KB LDS)
#define HIST_BLOCKS (NCH * NRNG)  // 256
#define CONV_BLOCKS 6250  // NN*HID/4 float4 / 256 exact
#define WPREP_BLOCKS 32   // 128 wave-units / 4
#define POOLZ_BLOCKS 64   // NG*HID/4 float4 / 256 exact
#define PH_GRID (HIST_BLOCKS + CONV_BLOCKS + WPREP_BLOCKS + POOLZ_BLOCKS)

__global__ __launch_bounds__(256) void prep_hist_kernel(const int* __restrict__ ei,
                                                        ushort* __restrict__ rank,
                                                        ushort* __restrict__ blockcnt,
                                                        const float* __restrict__ x,
                                                        ushort* __restrict__ xb,
                                                        const float* __restrict__ W0,
                                                        const float* __restrict__ W1,
                                                        const float* __restrict__ W2,
                                                        const float* __restrict__ W3,
                                                        ushort* __restrict__ Wp,
                                                        float* __restrict__ pooled) {
    __shared__ uint hh[HWORDS];  // 25KB -> 6 blocks/CU
    uint b = blockIdx.x;
    if (b < HIST_BLOCKS) {
        int c = b >> 2;   // edge chunk
        int r = b & 3;    // node range
        for (int i = threadIdx.x; i < HWORDS; i += 256) hh[i] = 0;
        __syncthreads();
        int base = c * CHE;
        int lo = r * HRNG;
        const int4* ev = (const int4*)(ei + NE + base);  // CHE%4==0, 16B aligned
        const int nvec = CHE / 4;                        // 3125
        int k4 = threadIdx.x;
        int4 cur;
        bool have = k4 < nvec;
        if (have) cur = ev[k4];
        while (have) {
            int kn = k4 + 256;
            bool hn = kn < nvec;
            int4 nxt;
            if (hn) nxt = ev[kn];  // prefetch next vector while atomics issue
            int e0 = base + k4 * 4;
#pragma unroll
            for (int j = 0; j < 4; ++j) {
                int d = (j == 0) ? cur.x : (j == 1) ? cur.y : (j == 2) ? cur.z : cur.w;
                int local = d - lo;
                if ((unsigned)local < (unsigned)HRNG) {
                    uint sh = (local & 1) << 4;
                    uint old = atomicAdd(&hh[local >> 1], 1u << sh);
                    rank[e0 + j] = (ushort)((old >> sh) & 0xffffu);
                }
            }
            k4 = kn;
            cur = nxt;
            have = hn;
        }
        __syncthreads();
        // coalesced writeback of this (chunk, range)'s counts
        uint* dstw = (uint*)(blockcnt + (size_t)c * NN) + r * HWORDS;
        for (int i = threadIdx.x; i < HWORDS; i += 256) dstw[i] = hh[i];
    } else if (b < HIST_BLOCKS + CONV_BLOCKS) {
        int i = (b - HIST_BLOCKS) * 256 + threadIdx.x;  // < 1,600,000 exactly
        float4 v = ((const float4*)x)[i];
        ushort4 o;
        o.x = f2bf(v.x);
        o.y = f2bf(v.y);
        o.z = f2bf(v.z);
        o.w = f2bf(v.w);
        ((ushort4*)xb)[i] = o;
    } else if (b < HIST_BLOCKS + CONV_BLOCKS + WPREP_BLOCKS) {
        int wu = (b - HIST_BLOCKS - CONV_BLOCKS) * 4 + (threadIdx.x >> 6);
        if (wu >= 128) return;
        int lane = threadIdx.x & 63;
        int m = wu >> 5;
        int g = wu & 31;
        int tile = g >> 2;
        int chunk = g & 3;
        const float* W = (m == 0) ? W0 : (m == 1) ? W1 : (m == 2) ? W2 : W3;
        int col = tile * 16 + (lane & 15);
        int k0 = chunk * 32 + (lane >> 4) * 8;
        ushort* dst = Wp + ((size_t)wu * 64 + lane) * 8;
#pragma unroll
        for (int j = 0; j < 8; ++j) dst[j] = f2bf(W[col * HID + k0 + j]);
    } else {
        int i = (b - HIST_BLOCKS - CONV_BLOCKS - WPREP_BLOCKS) * 256 + threadIdx.x;  // < 16384
        ((float4*)pooled)[i] = make_float4(0.f, 0.f, 0.f, 0.f);
    }
}

// ---------------------------------------------------------------------------
// Fused chunk-column scan + block-level deg scan (kept from R16).
// ---------------------------------------------------------------------------
__global__ __launch_bounds__(256) void scan1_kernel(ushort* __restrict__ blockcnt,
                                                    int* __restrict__ deg,
                                                    int* __restrict__ row_start,
                                                    int* __restrict__ bsums, int n) {
    __shared__ int wsum[4];
    __shared__ int degsh[256];
    int i = blockIdx.x * 256 + threadIdx.x;
    int w = blockIdx.x * 128 + (int)threadIdx.x;  // packed word = 2 nodes
    if (threadIdx.x < 128 && w < NN / 2) {
        uint run_lo = 0, run_hi = 0;
        uint* col = (uint*)blockcnt + w;
#pragma unroll 4
        for (int c = 0; c < NCH; ++c) {
            uint x = col[(size_t)c * (NN / 2)];
            col[(size_t)c * (NN / 2)] = run_lo | (run_hi << 16);
            run_lo += x & 0xffffu;
            run_hi += x >> 16;
        }
        degsh[2 * (int)threadIdx.x] = (int)run_lo;
        degsh[2 * (int)threadIdx.x + 1] = (int)run_hi;
        ((int2*)deg)[w] = make_int2((int)run_lo, (int)run_hi);
    }
    __syncthreads();
    int lane = threadIdx.x & 63;
    int wid = threadIdx.x >> 6;
    int v = (i < n) ? degsh[threadIdx.x] : 0;
    int sc = v;
#pragma unroll
    for (int off = 1; off < 64; off <<= 1) {
        int t = __shfl_up(sc, off);
        if (lane >= off) sc += t;
    }
    if (lane == 63) wsum[wid] = sc;
    __syncthreads();
    int wpre = 0;
#pragma unroll
    for (int k = 0; k < 4; ++k) wpre += (k < wid) ? wsum[k] : 0;
    if (i < n) row_start[i] = wpre + sc - v;  // block-exclusive
    if (threadIdx.x == 255) bsums[blockIdx.x] = wpre + sc;
}

// merged scan2+scan3: each block reduces bsums[0..blockIdx) and adds.
__global__ __launch_bounds__(256) void scan23_kernel(int* __restrict__ row_start,
                                                     const int* __restrict__ bsums, int n) {
    __shared__ int sred[4];
    int v = (threadIdx.x < blockIdx.x) ? bsums[threadIdx.x] : 0;
#pragma unroll
    for (int off = 32; off > 0; off >>= 1) v += __shfl_xor(v, off);
    if ((threadIdx.x & 63) == 0) sred[threadIdx.x >> 6] = v;
    __syncthreads();
    int total = sred[0] + sred[1] + sred[2] + sred[3];
    int i = blockIdx.x * 256 + threadIdx.x;
    if (i < n) row_start[i] += total;
}

// atomic-free fill, 4 edges/thread.
__global__ __launch_bounds__(256) void fill_kernel(const int* __restrict__ ei,
                                                   const int* __restrict__ row_start,
                                                   const ushort* __restrict__ rank,
                                                   const ushort* __restrict__ blockcnt,
                                                   ushort* __restrict__ srclist) {
    int e4 = blockIdx.x * 256 + threadIdx.x;
    if (e4 >= NE / 4) return;
    int4 src = ((const int4*)ei)[e4];
    int4 dst = ((const int4*)(ei + NE))[e4];
    ushort4 rk = ((const ushort4*)rank)[e4];
    int c = e4 / (CHE / 4);  // chunk id
    const ushort* off = blockcnt + (size_t)c * NN;
    int p0 = row_start[dst.x] + off[dst.x] + rk.x;
    int p1 = row_start[dst.y] + off[dst.y] + rk.y;
    int p2 = row_start[dst.z] + off[dst.z] + rk.z;
    int p3 = row_start[dst.w] + off[dst.w] + rk.w;
    srclist[p0] = (ushort)src.x;
    srclist[p1] = (ushort)src.y;
    srclist[p2] = (ushort)src.z;
    srclist[p3] = (ushort)src.w;
}

// ---------------------------------------------------------------------------
// FUSED SAGE layer (R23): R21 body + scalar wave-entry prefetch.
//   Wave entry: row_start/deg for all 4 nodes + the 4 first-chunk index
//   wave-loads (sla[4], one coalesced load each) -- no uint4 buffering.
//   Per node: R21's chunk loop (quarters via __shfl, predicated tail);
//   jb=0 uses the prefetched sla[i], jb>=64 (rare) loads inline.
//   Phase 2: GEMM col-tiles 2/wave, A-mean from LDS, A-root from feat.
// ---------------------------------------------------------------------------
template <bool POOL>
__global__ __launch_bounds__(256) void sage_fused(const ushort* __restrict__ feat,
                                                  const int* __restrict__ row_start,
                                                  const int* __restrict__ deg,
                                                  const ushort* __restrict__ srclist,
                                                  const ushort* __restrict__ WpL,
                                                  const float* __restrict__ bias,
                                                  const int* __restrict__ batch,
                                                  void* __restrict__ outv) {
    __shared__ ushort As[16][136];  // 4.25KB, padded rows
    int lane = threadIdx.x & 63;
    int wv = threadIdx.x >> 6;
    int base = blockIdx.x * 16;  // 3125 blocks * 16 = 50000 exact
    int cl = lane & 15;
    int sub = lane >> 4;
    const uint4* fb = (const uint4*)feat;  // row stride = 16 uint4 (256B)

    // ---- wave-entry prefetch: meta + first index chunk for all 4 nodes ----
    int nodes0 = base + wv * 4;
    int s0a[4], dda[4], sla[4];
#pragma unroll
    for (int i = 0; i < 4; ++i) {
        s0a[i] = row_start[nodes0 + i];
        dda[i] = deg[nodes0 + i];
    }
#pragma unroll
    for (int i = 0; i < 4; ++i) {
        int cm = max(dda[i] - 1, 0);
        sla[i] = (int)srclist[s0a[i] + min(lane, cm)];
    }

    // ---- Phase 1: aggregate 4 nodes on this wave (R21 body) ----
#pragma unroll 1
    for (int i = 0; i < 4; ++i) {
        int s0 = s0a[i];
        int d = dda[i];
        int dm1 = d - 1;

        float a[8];
#pragma unroll
        for (int k = 0; k < 8; ++k) a[k] = 0.f;

#pragma unroll 1
        for (int jb = 0; jb < d; jb += 64) {
            int sl = (jb == 0) ? sla[i] : (int)srclist[s0 + min(jb + lane, dm1)];
            int lim = min(jb + 64, d);
            int j = jb;
            for (; j + 16 <= lim; j += 16) {
                int b0 = j - jb;
                int i0 = __shfl(sl, b0 + sub);
                int i1 = __shfl(sl, b0 + 4 + sub);
                int i2 = __shfl(sl, b0 + 8 + sub);
                int i3 = __shfl(sl, b0 + 12 + sub);
                uint4 v0 = fb[(size_t)i0 * 16 + cl];
                uint4 v1 = fb[(size_t)i1 * 16 + cl];
                uint4 v2 = fb[(size_t)i2 * 16 + cl];
                uint4 v3 = fb[(size_t)i3 * 16 + cl];
                a[0] += (bf_lo(v0.x) + bf_lo(v1.x)) + (bf_lo(v2.x) + bf_lo(v3.x));
                a[1] += (bf_hi(v0.x) + bf_hi(v1.x)) + (bf_hi(v2.x) + bf_hi(v3.x));
                a[2] += (bf_lo(v0.y) + bf_lo(v1.y)) + (bf_lo(v2.y) + bf_lo(v3.y));
                a[3] += (bf_hi(v0.y) + bf_hi(v1.y)) + (bf_hi(v2.y) + bf_hi(v3.y));
                a[4] += (bf_lo(v0.z) + bf_lo(v1.z)) + (bf_lo(v2.z) + bf_lo(v3.z));
                a[5] += (bf_hi(v0.z) + bf_hi(v1.z)) + (bf_hi(v2.z) + bf_hi(v3.z));
                a[6] += (bf_lo(v0.w) + bf_lo(v1.w)) + (bf_lo(v2.w) + bf_lo(v3.w));
                a[7] += (bf_hi(v0.w) + bf_hi(v1.w)) + (bf_hi(v2.w) + bf_hi(v3.w));
            }
            if (j < lim) {  // tail round (last chunk only)
                int k0 = j + sub;
                int k1 = j + 4 + sub;
                int k2 = j + 8 + sub;
                int k3 = j + 12 + sub;
                int i0 = __shfl(sl, min(k0, dm1) - jb);
                int i1 = __shfl(sl, min(k1, dm1) - jb);
                int i2 = __shfl(sl, min(k2, dm1) - jb);
                int i3 = __shfl(sl, min(k3, dm1) - jb);
                uint4 v0 = make_uint4(0u, 0u, 0u, 0u);
                uint4 v1 = make_uint4(0u, 0u, 0u, 0u);
                uint4 v2 = make_uint4(0u, 0u, 0u, 0u);
                uint4 v3 = make_uint4(0u, 0u, 0u, 0u);
                if (k0 < d) v0 = fb[(size_t)i0 * 16 + cl];
                if (k1 < d) v1 = fb[(size_t)i1 * 16 + cl];
                if (k2 < d) v2 = fb[(size_t)i2 * 16 + cl];
                if (k3 < d) v3 = fb[(size_t)i3 * 16 + cl];
                a[0] += (bf_lo(v0.x) + bf_lo(v1.x)) + (bf_lo(v2.x) + bf_lo(v3.x));
                a[1] += (bf_hi(v0.x) + bf_hi(v1.x)) + (bf_hi(v2.x) + bf_hi(v3.x));
                a[2] += (bf_lo(v0.y) + bf_lo(v1.y)) + (bf_lo(v2.y) + bf_lo(v3.y));
                a[3] += (bf_hi(v0.y) + bf_hi(v1.y)) + (bf_hi(v2.y) + bf_hi(v3.y));
                a[4] += (bf_lo(v0.z) + bf_lo(v1.z)) + (bf_lo(v2.z) + bf_lo(v3.z));
                a[5] += (bf_hi(v0.z) + bf_hi(v1.z)) + (bf_hi(v2.z) + bf_hi(v3.z));
                a[6] += (bf_lo(v0.w) + bf_lo(v1.w)) + (bf_lo(v2.w) + bf_lo(v3.w));
                a[7] += (bf_hi(v0.w) + bf_hi(v1.w)) + (bf_hi(v2.w) + bf_hi(v3.w));
            }
        }

#pragma unroll
        for (int k = 0; k < 8; ++k) {
            float v = a[k];
            v += __shfl_xor(v, 16);
            v += __shfl_xor(v, 32);
            a[k] = v;
        }

        if (sub == 0) {
            float inv = 1.0f / fmaxf((float)d, 1.0f);
            uint4 o;
            o.x = (uint)f2bf(a[0] * inv) | ((uint)f2bf(a[1] * inv) << 16);
            o.y = (uint)f2bf(a[2] * inv) | ((uint)f2bf(a[3] * inv) << 16);
            o.z = (uint)f2bf(a[4] * inv) | ((uint)f2bf(a[5] * inv) << 16);
            o.w = (uint)f2bf(a[6] * inv) | ((uint)f2bf(a[7] * inv) << 16);
            *(uint4*)&As[wv * 4 + i][cl * 8] = o;
        }
    }
    __syncthreads();

    // ---- Phase 2: GEMM, col-tiles {wv*2, wv*2+1} ----
    int mrow = lane & 15;
    int quad = lane >> 4;

    f32x4 acc[2];
    acc[0] = (f32x4){0.f, 0.f, 0.f, 0.f};
    acc[1] = (f32x4){0.f, 0.f, 0.f, 0.f};

    const ushort* arow_r = feat + ((size_t)(base + mrow)) * HID + quad * 8;

#pragma unroll
    for (int half = 0; half < 2; ++half) {
        const ushort* wb = WpL + (size_t)half * 16384 + (size_t)lane * 8;
#pragma unroll
        for (int c = 0; c < 4; ++c) {
            bf16x8 a;
            if (half == 0) {
                a = *(const bf16x8*)&As[mrow][c * 32 + quad * 8];
            } else {
                a = *(const bf16x8*)(arow_r + c * 32);
            }
#pragma unroll
            for (int tt = 0; tt < 2; ++tt) {
                int t = wv * 2 + tt;
                bf16x8 b = *(const bf16x8*)(wb + (size_t)(t * 4 + c) * 512);
                acc[tt] = __builtin_amdgcn_mfma_f32_16x16x32_bf16(a, b, acc[tt], 0, 0, 0);
            }
        }
    }

    if (POOL) {
        float* pooled = (float*)outv;
        int rbase = base + quad * 4;
        int g0 = batch[rbase + 0];
        int g1 = batch[rbase + 1];
        int g2 = batch[rbase + 2];
        int g3 = batch[rbase + 3];
#pragma unroll
        for (int tt = 0; tt < 2; ++tt) {
            int col = (wv * 2 + tt) * 16 + mrow;
            float bv = bias[col];
            float v0 = acc[tt][0] + bv;
            float v1 = acc[tt][1] + bv;
            float v2 = acc[tt][2] + bv;
            float v3 = acc[tt][3] + bv;
            int cg = g0;
            float s = v0;
            if (g1 == cg) s += v1; else { atomicAdd(&pooled[(size_t)cg * HID + col], s); cg = g1; s = v1; }
            if (g2 == cg) s += v2; else { atomicAdd(&pooled[(size_t)cg * HID + col], s); cg = g2; s = v2; }
            if (g3 == cg) s += v3; else { atomicAdd(&pooled[(size_t)cg * HID + col], s); cg = g3; s = v3; }
            atomicAdd(&pooled[(size_t)cg * HID + col], s);
        }
    } else {
        ushort* out = (ushort*)outv;
#pragma unroll
        for (int tt = 0; tt < 2; ++tt) {
            int col = (wv * 2 + tt) * 16 + mrow;
            float bv = bias[col];
#pragma unroll
            for (int r = 0; r < 4; ++r) {
                int row = base + quad * 4 + r;
                out[(size_t)row * HID + col] = f2bf(acc[tt][r] + bv);
            }
        }
    }
}

// ---------------------------------------------------------------------------
// Tail: lin1 + BN(eval) + relu + lin2. One block (128 thr) per graph.
// ---------------------------------------------------------------------------
__global__ __launch_bounds__(128) void tail_kernel(const float* __restrict__ pooled,
                                                   const float* __restrict__ lin1_w,
                                                   const float* __restrict__ lin1_b,
                                                   const float* __restrict__ lin2_w,
                                                   const float* __restrict__ lin2_b,
                                                   const float* __restrict__ gamma,
                                                   const float* __restrict__ beta,
                                                   const float* __restrict__ rmean,
                                                   const float* __restrict__ rvar,
                                                   float* __restrict__ out) {
    __shared__ float Wt[64 * 128];  // Wt[k][c ^ (k&31)] = lin1_w[c][k0+k]
    __shared__ float p[128];
    __shared__ float tbuf[128];
    int g = blockIdx.x;
    int c = threadIdx.x;
    p[c] = pooled[g * HID + c];
    float acc = lin1_b[c];
    int kk = c & 63;
    int chalf = c >> 6;
    for (int k0 = 0; k0 < 128; k0 += 64) {
        __syncthreads();
        for (int i = 0; i < 64; ++i) {
            int crow = i * 2 + chalf;
            float v = lin1_w[crow * HID + k0 + kk];
            Wt[kk * 128 + (crow ^ (kk & 31))] = v;
        }
        __syncthreads();
#pragma unroll
        for (int k = 0; k < 64; ++k) {
            acc += p[k0 + k] * Wt[k * 128 + (c ^ (k & 31))];
        }
    }
    float v = (acc - rmean[c]) * rsqrtf(rvar[c] + BN_EPS) * gamma[c] + beta[c];
    v = fmaxf(v, 0.f);
    tbuf[c] = v;
    __syncthreads();
    int j = c >> 6;
    int lane = c & 63;
    float partial = tbuf[lane] * lin2_w[j * HID + lane] +
                    tbuf[lane + 64] * lin2_w[j * HID + lane + 64];
    for (int off = 32; off > 0; off >>= 1) partial += __shfl_down(partial, off);
    if (lane == 0) out[g * 2 + j] = partial + lin2_b[j];
}

// ---------------------------------------------------------------------------
extern "C" void kernel_launch(void* const* d_in, const int* in_sizes, int n_in,
                              void* d_out, int out_size, void* d_ws, size_t ws_size,
                              hipStream_t stream) {
    const float* x = (const float*)d_in[0];
    const int* ei = (const int*)d_in[1];      // [2][E]
    const int* batch = (const int*)d_in[2];   // [N]
    const float* W1l = (const float*)d_in[3];
    const float* b1 = (const float*)d_in[4];
    const float* W1r = (const float*)d_in[5];
    const float* W2l = (const float*)d_in[6];
    const float* b2 = (const float*)d_in[7];
    const float* W2r = (const float*)d_in[8];
    const float* lin1_w = (const float*)d_in[9];
    const float* lin1_b = (const float*)d_in[10];
    const float* lin2_w = (const float*)d_in[11];
    const float* lin2_b = (const float*)d_in[12];
    const float* gamma = (const float*)d_in[13];
    const float* beta = (const float*)d_in[14];
    const float* rmean = (const float*)d_in[15];
    const float* rvar = (const float*)d_in[16];
    float* out = (float*)d_out;

    const int N = NN, E = NE;

    // workspace carve (256B aligned)
    char* p = (char*)d_ws;
    auto carve = [&](size_t bytes) {
        void* r = (void*)p;
        p += (bytes + 255) & ~(size_t)255;
        return r;
    };
    int* deg = (int*)carve((size_t)N * 4);
    int* row_start = (int*)carve((size_t)N * 4);
    int* bsums = (int*)carve(1024 * 4);
    ushort* rank = (ushort*)carve((size_t)E * 2);
    ushort* blockcnt = (ushort*)carve((size_t)NCH * NN * 2);  // 6.4 MB
    ushort* srclist = (ushort*)carve((size_t)E * 2 + 64);
    ushort* xb = (ushort*)carve((size_t)N * HID * 2);
    ushort* h1 = (ushort*)carve((size_t)N * HID * 2);
    float* pooled = (float*)carve((size_t)NG * HID * 4);
    ushort* Wp = (ushort*)carve(4 * 32 * 64 * 8 * 2);  // 128 KB

    // merged front-end: LDS hist + convert + weight pack + pooled zero.
    prep_hist_kernel<<<PH_GRID, 256, 0, stream>>>(ei, rank, blockcnt, x, xb,
                                                  W1l, W1r, W2l, W2r, Wp, pooled);

    // fused chunk-column scan + block deg scan, then cross-block fixup
    const int scanBlocks = (N + 255) / 256;  // 196
    scan1_kernel<<<scanBlocks, 256, 0, stream>>>(blockcnt, deg, row_start, bsums, N);
    scan23_kernel<<<scanBlocks, 256, 0, stream>>>(row_start, bsums, N);
    fill_kernel<<<(E / 4 + 255) / 256, 256, 0, stream>>>(ei, row_start, rank, blockcnt, srclist);

    // fused layers: 3125 blocks x 4 waves x 4 nodes (R19 shape)
    sage_fused<false><<<N / 16, 256, 0, stream>>>(xb, row_start, deg, srclist, Wp, b1,
                                                  nullptr, h1);
    sage_fused<true><<<N / 16, 256, 0, stream>>>(h1, row_start, deg, srclist, Wp + 32768, b2,
                                                 batch, pooled);
    // tail
    tail_kernel<<<NG, 128, 0, stream>>>(pooled, lin1_w, lin1_b, lin2_w, lin2_b,
                                        gamma, beta, rmean, rvar, out);
}